// Round 11
// baseline (461.222 us; speedup 1.0000x reference)
//
#include <hip/hip_runtime.h>
#include <hip/hip_bf16.h>
#include <math.h>

typedef __bf16 bf16;
typedef __bf16 bf16x8 __attribute__((ext_vector_type(8)));
typedef __bf16 bf16x4 __attribute__((ext_vector_type(4)));
typedef float f32x4 __attribute__((ext_vector_type(4)));

#define KM 32768   // B*T

__device__ __forceinline__ void gload16(const void* g, void* l) {
  __builtin_amdgcn_global_load_lds((const __attribute__((address_space(1))) void*)g,
                                   (__attribute__((address_space(3))) void*)l, 16, 0, 0);
}

__device__ __forceinline__ float gelu_exact(float x) {
  return 0.5f * x * (1.0f + erff(x * 0.70710678118654752f));
}

// ---------------- fuse inputs + all weight transposes, one dispatch ----------------
__global__ void fuse_transpose_kernel(const float* __restrict__ tr, const float* __restrict__ se,
                                      const float* __restrict__ pr, bf16* __restrict__ Xb,
                                      const float* __restrict__ W_in, const float* __restrict__ W_m1,
                                      const float* __restrict__ W_m2, const float* __restrict__ W_o1,
                                      bf16* __restrict__ WbIn, bf16* __restrict__ WbM1,
                                      bf16* __restrict__ WbM2, bf16* __restrict__ WbO1) {
  int bid = blockIdx.x;
  if (bid < 34816) {   // fuse: 34816 blocks x 256 thr x 4 elems = 32768*1088
    int g = bid * 256 + threadIdx.x;
    int m = g / 272;
    int k0 = (g - m * 272) * 4;
    float4 v;
    if (k0 < 512)       v = *reinterpret_cast<const float4*>(tr + (size_t)m * 512 + k0);
    else if (k0 < 1024) v = *reinterpret_cast<const float4*>(se + (size_t)m * 512 + (k0 - 512));
    else                v = *reinterpret_cast<const float4*>(pr + (size_t)m * 64 + (k0 - 1024));
    union { bf16 h[4]; ushort4 u; } p;
    p.h[0] = (bf16)v.x; p.h[1] = (bf16)v.y; p.h[2] = (bf16)v.z; p.h[3] = (bf16)v.w;
    *reinterpret_cast<ushort4*>(Xb + (size_t)m * 1088 + k0) = p.u;
    return;
  }
  __shared__ float t[32][33];
  int b = bid - 34816;
  const float* W; bf16* Wt; int K, N, kb, nb;
  if (b < 1088)      { W = W_in; Wt = WbIn; K = 1088; N = 1024; kb = b % 34;  nb = b / 34; }
  else if (b < 2112) { int c = b - 1088; W = W_m1; Wt = WbM1; K = 1024; N = 1024; kb = c & 31; nb = c >> 5; }
  else if (b < 3136) { int c = b - 2112; W = W_m2; Wt = WbM2; K = 1024; N = 1024; kb = c & 31; nb = c >> 5; }
  else               { int c = b - 3136; W = W_o1; Wt = WbO1; K = 1024; N = 512;  kb = c & 31; nb = c >> 5; }
  int k0 = kb * 32, n0 = nb * 32;
  int tx = threadIdx.x & 31, ty = threadIdx.x >> 5;  // 32 x 8
  #pragma unroll
  for (int j = 0; j < 32; j += 8) t[ty + j][tx] = W[(size_t)(k0 + ty + j) * N + n0 + tx];
  __syncthreads();
  #pragma unroll
  for (int j = 0; j < 32; j += 8)
    Wt[(size_t)(n0 + ty + j) * K + k0 + tx] = (bf16)t[tx][ty + j];
}

// ======== 128x128 MFMA GEMM, 16x16 frags, BK=64, DOUBLE-BUFFERED single-barrier ========
// T3 minimum 2-phase: stage tile t+1 into buf^1 BEFORE ds_reads of buf[t];
// one __syncthreads per K-tile (implicit vmcnt(0) lands the prefetch issued a tile ago).
// A bf16 [M][K] via global_load_lds; Bt [N][K] bf16. T1 XCD-chunked swizzle.
// OBJ=1: no C write; epilogue: per-row partial dot with w2 -> objp[bn*2+wn][row].
template<int ACT, bool RES, bool OBJ>
__global__ void gemm_kernel(const bf16* __restrict__ A, const bf16* __restrict__ Bt,
                            const float* __restrict__ bias, const bf16* __restrict__ res,
                            bf16* __restrict__ C, const float* __restrict__ w2,
                            float* __restrict__ objp, int N, int K, int nbn) {
  __shared__ __align__(16) bf16 lds[2][2][128 * 64];   // [buf][A/B][row*64]
  int nwg = gridDim.x;
  int bid0 = blockIdx.x;
  int bid = (nwg & 7) ? bid0 : ((bid0 & 7) * (nwg >> 3) + (bid0 >> 3));
  int bn = bid % nbn, bm = bid / nbn;
  int tid = threadIdx.x;
  int w = tid >> 6, L = tid & 63;
  int wm = w >> 1, wn = w & 1;
  // staging: inverse-swizzled global source, linear LDS dest (ERRATA #21; conflicts=0)
  int srow = L >> 3;
  int scol = 8 * ((L & 7) ^ srow);
  const bf16* Ab = A + (size_t)(bm * 128) * K;
  const bf16* Bb = Bt + (size_t)(bn * 128) * K;
  int nkt = (K + 63) >> 6;
  auto stage = [&](int tt) {
    int bb = tt & 1;
    int k0 = tt << 6;
    #pragma unroll
    for (int i = 0; i < 4; ++i) {
      int row = w * 32 + i * 8;
      gload16(Ab + (size_t)(row + srow) * K + k0 + scol, &lds[bb][0][row * 64]);
      gload16(Bb + (size_t)(row + srow) * K + k0 + scol, &lds[bb][1][row * 64]);
    }
  };
  f32x4 acc[4][4] = {};
  stage(0);
  __syncthreads();
  for (int kt = 0; kt < nkt; ++kt) {
    // issue next tile's stage FIRST (into the other buffer) — HBM latency hides under
    // this tile's LDS reads + MFMA; drained by the single barrier below.
    if (kt + 1 < nkt) stage(kt + 1);
    const bf16* As = lds[kt & 1][0];
    const bf16* Bs = lds[kt & 1][1];
    #pragma unroll
    for (int kk = 0; kk < 2; ++kk) {
      bf16x8 af[4], bfr[4];
      int cb = kk * 64 + ((L >> 4) * 16);
      #pragma unroll
      for (int m = 0; m < 4; ++m) {
        int r = wm * 64 + m * 16 + (L & 15);
        int addr = r * 128 + (cb ^ ((r & 7) << 4));
        af[m] = *reinterpret_cast<const bf16x8*>(
            reinterpret_cast<const char*>(As) + addr);
      }
      #pragma unroll
      for (int n = 0; n < 4; ++n) {
        int r = wn * 64 + n * 16 + (L & 15);
        int addr = r * 128 + (cb ^ ((r & 7) << 4));
        bfr[n] = *reinterpret_cast<const bf16x8*>(
            reinterpret_cast<const char*>(Bs) + addr);
      }
      #pragma unroll
      for (int m = 0; m < 4; ++m)
        #pragma unroll
        for (int n = 0; n < 4; ++n)
          acc[m][n] = __builtin_amdgcn_mfma_f32_16x16x32_bf16(af[m], bfr[n], acc[m][n], 0, 0, 0);
    }
    __syncthreads();   // ONE barrier per tile: drains vmcnt (prefetch landed) + lgkm
  }
  // ---- epilogue: D row = (L>>4)*4 + reg, col = L&15  [m89-verified] ----
  int cn0 = bn * 128 + wn * 64;
  float bv[4];
  #pragma unroll
  for (int n = 0; n < 4; ++n) bv[n] = bias[cn0 + n * 16 + (L & 15)];
  if (OBJ) {
    float w2v[4];
    #pragma unroll
    for (int n = 0; n < 4; ++n) w2v[n] = w2[cn0 + n * 16 + (L & 15)];
    float* op = objp + (size_t)(bn * 2 + wn) * KM;
    #pragma unroll
    for (int m = 0; m < 4; ++m) {
      int grow0 = bm * 128 + wm * 64 + m * 16 + ((L >> 4) << 2);
      #pragma unroll
      for (int r = 0; r < 4; ++r) {
        float s = 0.f;
        #pragma unroll
        for (int n = 0; n < 4; ++n) {
          float v = gelu_exact(acc[m][n][r] + bv[n]);
          s += v * w2v[n];
        }
        s += __shfl_xor(s, 1); s += __shfl_xor(s, 2);
        s += __shfl_xor(s, 4); s += __shfl_xor(s, 8);
        if ((L & 15) == 0) op[grow0 + r] = s;
      }
    }
  } else {
    #pragma unroll
    for (int m = 0; m < 4; ++m) {
      int grow0 = bm * 128 + wm * 64 + m * 16 + ((L >> 4) << 2);
      #pragma unroll
      for (int r = 0; r < 4; ++r) {
        size_t ro = (size_t)(grow0 + r) * N;
        #pragma unroll
        for (int n = 0; n < 4; ++n) {
          float v = acc[m][n][r] + bv[n];
          if (ACT == 1) v = gelu_exact(v);
          int col = cn0 + n * 16 + (L & 15);
          if (RES) v += (float)res[ro + col];
          C[ro + col] = (bf16)v;
        }
      }
    }
  }
}

// ---------------- LayerNorm, one row per WAVE (no barriers) ----------------
__global__ void ln_wave_kernel(bf16* __restrict__ X, const float* __restrict__ g,
                               const float* __restrict__ b) {
  int w = threadIdx.x >> 6, L = threadIdx.x & 63;
  size_t row = (size_t)blockIdx.x * 4 + w;
  bf16* xr = X + row * 1024 + L * 16;
  bf16x8 v0 = *reinterpret_cast<const bf16x8*>(xr);
  bf16x8 v1 = *reinterpret_cast<const bf16x8*>(xr + 8);
  float x[16];
  #pragma unroll
  for (int i = 0; i < 8; ++i) { x[i] = (float)v0[i]; x[8 + i] = (float)v1[i]; }
  float s = 0.f;
  #pragma unroll
  for (int i = 0; i < 16; ++i) s += x[i];
  #pragma unroll
  for (int off = 32; off > 0; off >>= 1) s += __shfl_xor(s, off);
  float mu = s * (1.0f / 1024.0f);
  float sq = 0.f;
  #pragma unroll
  for (int i = 0; i < 16; ++i) { x[i] -= mu; sq += x[i] * x[i]; }
  #pragma unroll
  for (int off = 32; off > 0; off >>= 1) sq += __shfl_xor(sq, off);
  float rs = rsqrtf(sq * (1.0f / 1024.0f) + 1e-5f);
  const float4* gp = reinterpret_cast<const float4*>(g + L * 16);
  const float4* bp = reinterpret_cast<const float4*>(b + L * 16);
  bf16x8 o0, o1;
  #pragma unroll
  for (int q = 0; q < 4; ++q) {
    float4 gv = gp[q], bv = bp[q];
    int i = q * 4;
    float r0 = x[i] * rs * gv.x + bv.x;
    float r1 = x[i + 1] * rs * gv.y + bv.y;
    float r2 = x[i + 2] * rs * gv.z + bv.z;
    float r3 = x[i + 3] * rs * gv.w + bv.w;
    if (q < 2) { o0[i] = (bf16)r0; o0[i + 1] = (bf16)r1; o0[i + 2] = (bf16)r2; o0[i + 3] = (bf16)r3; }
    else { o1[i - 8] = (bf16)r0; o1[i - 7] = (bf16)r1; o1[i - 6] = (bf16)r2; o1[i - 5] = (bf16)r3; }
  }
  *reinterpret_cast<bf16x8*>(xr) = o0;
  *reinterpret_cast<bf16x8*>(xr + 8) = o1;
}

// ---------------- attn logits via MFMA -> raw logits DIRECT to out_attn ----------------
__global__ void attn_logits_mfma(const bf16* __restrict__ seq, const float* __restrict__ tq,
                                 const float* __restrict__ objp, const float* __restrict__ b2,
                                 float* __restrict__ logits, float* __restrict__ out_obj) {
  __shared__ bf16 tqs[16][1032];
  int tid = threadIdx.x;
  for (int i = tid; i < 4096; i += 256) {
    int idx = i * 4;
    int n = idx >> 10, k = idx & 1023;
    float4 v = *reinterpret_cast<const float4*>(tq + idx);
    bf16x4 p; p[0] = (bf16)v.x; p[1] = (bf16)v.y; p[2] = (bf16)v.z; p[3] = (bf16)v.w;
    *reinterpret_cast<bf16x4*>(&tqs[n][k]) = p;
  }
  __syncthreads();
  int w = tid >> 6, L = tid & 63;
  int row0 = blockIdx.x * 128 + w * 32;
  const bf16* A0 = seq + (size_t)(row0 + (L & 15)) * 1024 + ((L >> 4) * 8);
  const bf16* Bq = &tqs[L & 15][(L >> 4) * 8];
  f32x4 acc0 = {}, acc1 = {};
  #pragma unroll 4
  for (int kt = 0; kt < 32; ++kt) {
    int k0 = kt * 32;
    bf16x8 bq = *reinterpret_cast<const bf16x8*>(Bq + k0);
    bf16x8 a0 = *reinterpret_cast<const bf16x8*>(A0 + k0);
    bf16x8 a1 = *reinterpret_cast<const bf16x8*>(A0 + 16 * 1024 + k0);
    acc0 = __builtin_amdgcn_mfma_f32_16x16x32_bf16(a0, bq, acc0, 0, 0, 0);
    acc1 = __builtin_amdgcn_mfma_f32_16x16x32_bf16(a1, bq, acc1, 0, 0, 0);
  }
  float b2v = b2[0];
  int b = row0 >> 12;
  int n = L & 15;
  float* outn = logits + ((size_t)(b * 16) + n) * 4096;
  #pragma unroll
  for (int mf = 0; mf < 2; ++mf) {
    int mrow = row0 + mf * 16 + ((L >> 4) << 2);
    float os0 = 0.f, os1 = 0.f, os2 = 0.f, os3 = 0.f;
    #pragma unroll
    for (int p = 0; p < 8; ++p) {
      float4 t = *reinterpret_cast<const float4*>(objp + (size_t)p * KM + mrow);
      os0 += t.x; os1 += t.y; os2 += t.z; os3 += t.w;
    }
    float ob[4];
    ob[0] = 1.0f / (1.0f + expf(-(os0 + b2v)));
    ob[1] = 1.0f / (1.0f + expf(-(os1 + b2v)));
    ob[2] = 1.0f / (1.0f + expf(-(os2 + b2v)));
    ob[3] = 1.0f / (1.0f + expf(-(os3 + b2v)));
    #pragma unroll
    for (int r = 0; r < 4; ++r) {
      int m = mrow + r;
      float v = (mf == 0 ? acc0[r] : acc1[r]) * 0.03125f + 1.5f * ob[r];
      outn[m & 4095] = v;
    }
    if (n == 0) {
      float4 o4 = make_float4(ob[0], ob[1], ob[2], ob[3]);
      *reinterpret_cast<float4*>(out_obj + mrow) = o4;
    }
  }
}

// ---------------- softmax over T=4096 per (b,n), IN-PLACE on out_attn ----------------
__global__ void softmax_kernel(float* __restrict__ attn) {
  __shared__ float sb[4];
  size_t row = blockIdx.x;
  float* orow = attn + row * 4096;
  int tid = threadIdx.x;
  float x[16];
  #pragma unroll
  for (int i = 0; i < 4; ++i) {
    float4 v = *reinterpret_cast<const float4*>(orow + tid * 16 + i * 4);
    x[i * 4 + 0] = v.x; x[i * 4 + 1] = v.y; x[i * 4 + 2] = v.z; x[i * 4 + 3] = v.w;
  }
  float mx = -1e30f;
  #pragma unroll
  for (int j = 0; j < 16; ++j) mx = fmaxf(mx, x[j]);
  #pragma unroll
  for (int off = 32; off > 0; off >>= 1) mx = fmaxf(mx, __shfl_xor(mx, off));
  if ((tid & 63) == 0) sb[tid >> 6] = mx;
  __syncthreads();
  mx = fmaxf(fmaxf(sb[0], sb[1]), fmaxf(sb[2], sb[3]));
  __syncthreads();
  float s = 0.f;
  #pragma unroll
  for (int j = 0; j < 16; ++j) { x[j] = expf(x[j] - mx); s += x[j]; }
  #pragma unroll
  for (int off = 32; off > 0; off >>= 1) s += __shfl_xor(s, off);
  if ((tid & 63) == 0) sb[tid >> 6] = s;
  __syncthreads();
  float inv = 1.0f / (sb[0] + sb[1] + sb[2] + sb[3]);
  #pragma unroll
  for (int i = 0; i < 4; ++i) {
    float4 v = make_float4(x[i * 4] * inv, x[i * 4 + 1] * inv, x[i * 4 + 2] * inv, x[i * 4 + 3] * inv);
    *reinterpret_cast<float4*>(orow + tid * 16 + i * 4) = v;
  }
}

// ---------------- token_values: sum_t attn[b,n,t]*seq[b,t,h], T split 16 ways ----------------
__global__ void token_values_kernel(const float* __restrict__ attn, const bf16* __restrict__ seq,
                                    float* __restrict__ tvp) {
  int bid = blockIdx.x;
  int split = bid & 15;
  int hc = (bid >> 4) & 15;
  int b = bid >> 8;
  __shared__ float al[16][256];
  int h = hc * 64 + (threadIdx.x & 63);
  int grp = threadIdx.x >> 6;  // 4 groups x 4 n each
  int t0 = split * 256;
  for (int i = threadIdx.x; i < 4096; i += 256)
    al[i >> 8][i & 255] = attn[((size_t)b * 16 + (i >> 8)) * 4096 + t0 + (i & 255)];
  __syncthreads();
  float acc[4] = {0.f, 0.f, 0.f, 0.f};
  for (int tt = 0; tt < 256; ++tt) {
    float s = (float)seq[((size_t)b * 4096 + t0 + tt) * 1024 + h];
    #pragma unroll
    for (int i = 0; i < 4; ++i) acc[i] += al[grp * 4 + i][tt] * s;
  }
  #pragma unroll
  for (int i = 0; i < 4; ++i)
    tvp[(size_t)split * 131072 + ((size_t)b * 16 + grp * 4 + i) * 1024 + h] = acc[i];
}

// ---------------- final LN: LN(tq + sum_16_parts(tv)) -> fp32 out ----------------
__global__ void final_ln_kernel(const float* __restrict__ tq, const float* __restrict__ tvp,
                                const float* __restrict__ g, const float* __restrict__ bb,
                                float* __restrict__ out0) {
  __shared__ float sb[4];
  int row = blockIdx.x;
  int n = row & 15;
  int tid = threadIdx.x;
  float x[4];
  #pragma unroll
  for (int i = 0; i < 4; ++i) {
    int h = tid * 4 + i;
    float v = tq[n * 1024 + h];
    #pragma unroll
    for (int p = 0; p < 16; ++p) v += tvp[(size_t)p * 131072 + (size_t)row * 1024 + h];
    x[i] = v;
  }
  float s = x[0] + x[1] + x[2] + x[3];
  #pragma unroll
  for (int off = 32; off > 0; off >>= 1) s += __shfl_xor(s, off);
  if ((tid & 63) == 0) sb[tid >> 6] = s;
  __syncthreads();
  float mu = (sb[0] + sb[1] + sb[2] + sb[3]) * (1.0f / 1024.0f);
  __syncthreads();
  float d[4], sq = 0.f;
  #pragma unroll
  for (int i = 0; i < 4; ++i) { d[i] = x[i] - mu; sq += d[i] * d[i]; }
  #pragma unroll
  for (int off = 32; off > 0; off >>= 1) sq += __shfl_xor(sq, off);
  if ((tid & 63) == 0) sb[tid >> 6] = sq;
  __syncthreads();
  float var = (sb[0] + sb[1] + sb[2] + sb[3]) * (1.0f / 1024.0f);
  float rs = rsqrtf(var + 1e-5f);
  #pragma unroll
  for (int i = 0; i < 4; ++i) {
    int h = tid * 4 + i;
    out0[(size_t)row * 1024 + h] = d[i] * rs * g[h] + bb[h];
  }
}

extern "C" void kernel_launch(void* const* d_in, const int* in_sizes, int n_in,
                              void* d_out, int out_size, void* d_ws, size_t ws_size,
                              hipStream_t stream) {
  const float* tr      = (const float*)d_in[0];
  const float* se      = (const float*)d_in[1];
  const float* pr      = (const float*)d_in[2];
  const float* W_in    = (const float*)d_in[3];
  const float* b_in    = (const float*)d_in[4];
  const float* ln_in_g = (const float*)d_in[5];
  const float* ln_in_b = (const float*)d_in[6];
  const float* W_m1    = (const float*)d_in[7];
  const float* b_m1    = (const float*)d_in[8];
  const float* W_m2    = (const float*)d_in[9];
  const float* b_m2    = (const float*)d_in[10];
  const float* W_o1    = (const float*)d_in[11];
  const float* b_o1    = (const float*)d_in[12];
  const float* W_o2    = (const float*)d_in[13];
  const float* b_o2    = (const float*)d_in[14];
  const float* tq      = (const float*)d_in[15];
  const float* ln_out_g= (const float*)d_in[16];
  const float* ln_out_b= (const float*)d_in[17];

  float* out       = (float*)d_out;
  float* out_state = out;                       // [8,16,1024]
  float* out_attn  = out + 131072;              // [8,16,4096]
  float* out_obj   = out + 131072 + 524288;     // [8,4096]

  char* ws = (char*)d_ws;
  size_t off = 0;
  auto alloc = [&](size_t bytes) {
    char* p = ws + off;
    off += (bytes + 255) & ~(size_t)255;
    return p;
  };
  bf16*  Xb   = (bf16*)alloc(71303168);   // fused input; reused as t1
  bf16*  t1   = Xb;
  bf16*  hb   = (bf16*)alloc(67108864);   // h (residual source)
  bf16*  sq   = (bf16*)alloc(67108864);   // h+mlp -> seq_hidden (LN in place)
  bf16*  WbIn = (bf16*)alloc(2228224);
  bf16*  WbM1 = (bf16*)alloc(2097152);
  bf16*  WbM2 = (bf16*)alloc(2097152);
  bf16*  WbO1 = (bf16*)alloc(1048576);
  float* objp = (float*)alloc(8 * KM * 4);   // 8 deterministic obj partials per row
  float* tvp  = (float*)alloc(16 * 131072 * 4);  // 16 tv partials

  fuse_transpose_kernel<<<34816 + 3648, 256, 0, stream>>>(
      tr, se, pr, Xb, W_in, W_m1, W_m2, W_o1, WbIn, WbM1, WbM2, WbO1);

  // h = fused@W_in + b_in
  gemm_kernel<0, false, false><<<2048, 256, 0, stream>>>(
      Xb, WbIn, b_in, nullptr, hb, nullptr, nullptr, 1024, 1088, 8);
  // t1 = gelu(h@W_m1 + b_m1)
  gemm_kernel<1, false, false><<<2048, 256, 0, stream>>>(
      hb, WbM1, b_m1, nullptr, t1, nullptr, nullptr, 1024, 1024, 8);
  // s = h + (t1@W_m2 + b_m2)
  gemm_kernel<0, true, false><<<2048, 256, 0, stream>>>(
      t1, WbM2, b_m2, hb, sq, nullptr, nullptr, 1024, 1024, 8);
  // seq_hidden = LN(s)  — one row per wave
  ln_wave_kernel<<<8192, 256, 0, stream>>>(sq, ln_in_g, ln_in_b);
  // objectness partials: gelu(seq@W_o1+b_o1) . W_o2  (no o1 materialization)
  gemm_kernel<1, false, true><<<1024, 256, 0, stream>>>(
      sq, WbO1, b_o1, nullptr, nullptr, W_o2, objp, 512, 1024, 4);
  // attn raw logits -> out_attn directly; sigmoid(obj) -> out_obj
  attn_logits_mfma<<<256, 256, 0, stream>>>(sq, tq, objp, b_o2, out_attn, out_obj);
  // softmax in place
  softmax_kernel<<<128, 256, 0, stream>>>(out_attn);
  // token values (16-way split) + final LN
  token_values_kernel<<<2048, 256, 0, stream>>>(out_attn, sq, tvp);
  final_ln_kernel<<<128, 256, 0, stream>>>(tq, tvp, ln_out_g, ln_out_b, out_state);
}

// Round 12
// 415.208 us; speedup vs baseline: 1.1108x; 1.1108x over previous
//
#include <hip/hip_runtime.h>
#include <hip/hip_bf16.h>
#include <math.h>

typedef __bf16 bf16;
typedef __bf16 bf16x8 __attribute__((ext_vector_type(8)));
typedef __bf16 bf16x4 __attribute__((ext_vector_type(4)));
typedef float f32x4 __attribute__((ext_vector_type(4)));

#define KM 32768   // B*T

__device__ __forceinline__ void gload16(const void* g, void* l) {
  __builtin_amdgcn_global_load_lds((const __attribute__((address_space(1))) void*)g,
                                   (__attribute__((address_space(3))) void*)l, 16, 0, 0);
}

__device__ __forceinline__ float gelu_exact(float x) {
  return 0.5f * x * (1.0f + erff(x * 0.70710678118654752f));
}

// ---------------- fuse inputs + all weight transposes, one dispatch ----------------
__global__ void fuse_transpose_kernel(const float* __restrict__ tr, const float* __restrict__ se,
                                      const float* __restrict__ pr, bf16* __restrict__ Xb,
                                      const float* __restrict__ W_in, const float* __restrict__ W_m1,
                                      const float* __restrict__ W_m2, const float* __restrict__ W_o1,
                                      bf16* __restrict__ WbIn, bf16* __restrict__ WbM1,
                                      bf16* __restrict__ WbM2, bf16* __restrict__ WbO1) {
  int bid = blockIdx.x;
  if (bid < 34816) {   // fuse: 34816 blocks x 256 thr x 4 elems = 32768*1088
    int g = bid * 256 + threadIdx.x;
    int m = g / 272;
    int k0 = (g - m * 272) * 4;
    float4 v;
    if (k0 < 512)       v = *reinterpret_cast<const float4*>(tr + (size_t)m * 512 + k0);
    else if (k0 < 1024) v = *reinterpret_cast<const float4*>(se + (size_t)m * 512 + (k0 - 512));
    else                v = *reinterpret_cast<const float4*>(pr + (size_t)m * 64 + (k0 - 1024));
    union { bf16 h[4]; ushort4 u; } p;
    p.h[0] = (bf16)v.x; p.h[1] = (bf16)v.y; p.h[2] = (bf16)v.z; p.h[3] = (bf16)v.w;
    *reinterpret_cast<ushort4*>(Xb + (size_t)m * 1088 + k0) = p.u;
    return;
  }
  __shared__ float t[32][33];
  int b = bid - 34816;
  const float* W; bf16* Wt; int K, N, kb, nb;
  if (b < 1088)      { W = W_in; Wt = WbIn; K = 1088; N = 1024; kb = b % 34;  nb = b / 34; }
  else if (b < 2112) { int c = b - 1088; W = W_m1; Wt = WbM1; K = 1024; N = 1024; kb = c & 31; nb = c >> 5; }
  else if (b < 3136) { int c = b - 2112; W = W_m2; Wt = WbM2; K = 1024; N = 1024; kb = c & 31; nb = c >> 5; }
  else               { int c = b - 3136; W = W_o1; Wt = WbO1; K = 1024; N = 512;  kb = c & 31; nb = c >> 5; }
  int k0 = kb * 32, n0 = nb * 32;
  int tx = threadIdx.x & 31, ty = threadIdx.x >> 5;  // 32 x 8
  #pragma unroll
  for (int j = 0; j < 32; j += 8) t[ty + j][tx] = W[(size_t)(k0 + ty + j) * N + n0 + tx];
  __syncthreads();
  #pragma unroll
  for (int j = 0; j < 32; j += 8)
    Wt[(size_t)(n0 + ty + j) * K + k0 + tx] = (bf16)t[tx][ty + j];
}

// ======== 128x128 MFMA GEMM (proven 16x16 frags), BK=64, 4 waves, T1 XCD swizzle ========
// A bf16 [M][K] via global_load_lds; Bt [N][K] bf16.
// OBJ=1: no C write; epilogue: per-row partial dot with w2 -> objp[bn*2+wn][row].
template<int ACT, bool RES, bool OBJ>
__global__ void gemm_kernel(const bf16* __restrict__ A, const bf16* __restrict__ Bt,
                            const float* __restrict__ bias, const bf16* __restrict__ res,
                            bf16* __restrict__ C, const float* __restrict__ w2,
                            float* __restrict__ objp, int N, int K, int nbn) {
  __shared__ __align__(16) bf16 lds[2][128 * 64];
  int nwg = gridDim.x;
  int bid0 = blockIdx.x;
  int bid = (nwg & 7) ? bid0 : ((bid0 & 7) * (nwg >> 3) + (bid0 >> 3));
  int bn = bid % nbn, bm = bid / nbn;
  int tid = threadIdx.x;
  int w = tid >> 6, L = tid & 63;
  int wm = w >> 1, wn = w & 1;
  // staging: inverse-swizzled global source, linear LDS dest (ERRATA #21; conflicts=0)
  int srow = L >> 3;
  int scol = 8 * ((L & 7) ^ srow);
  const bf16* Ab = A + (size_t)(bm * 128) * K;
  const bf16* Bb = Bt + (size_t)(bn * 128) * K;
  f32x4 acc[4][4] = {};
  int nkt = (K + 63) >> 6;
  for (int kt = 0; kt < nkt; ++kt) {
    int k0 = kt << 6;
    #pragma unroll
    for (int i = 0; i < 4; ++i) {
      int row = w * 32 + i * 8;
      gload16(Ab + (size_t)(row + srow) * K + k0 + scol, &lds[0][row * 64]);
      gload16(Bb + (size_t)(row + srow) * K + k0 + scol, &lds[1][row * 64]);
    }
    __syncthreads();   // compiler drains vmcnt before s_barrier
    #pragma unroll
    for (int kk = 0; kk < 2; ++kk) {
      bf16x8 af[4], bfr[4];
      int cb = kk * 64 + ((L >> 4) * 16);
      #pragma unroll
      for (int m = 0; m < 4; ++m) {
        int r = wm * 64 + m * 16 + (L & 15);
        int addr = r * 128 + (cb ^ ((r & 7) << 4));
        af[m] = *reinterpret_cast<const bf16x8*>(
            reinterpret_cast<const char*>(&lds[0][0]) + addr);
      }
      #pragma unroll
      for (int n = 0; n < 4; ++n) {
        int r = wn * 64 + n * 16 + (L & 15);
        int addr = r * 128 + (cb ^ ((r & 7) << 4));
        bfr[n] = *reinterpret_cast<const bf16x8*>(
            reinterpret_cast<const char*>(&lds[1][0]) + addr);
      }
      #pragma unroll
      for (int m = 0; m < 4; ++m)
        #pragma unroll
        for (int n = 0; n < 4; ++n)
          acc[m][n] = __builtin_amdgcn_mfma_f32_16x16x32_bf16(af[m], bfr[n], acc[m][n], 0, 0, 0);
    }
    __syncthreads();
  }
  // ---- epilogue: D row = (L>>4)*4 + reg, col = L&15  [m89-verified] ----
  int cn0 = bn * 128 + wn * 64;
  float bv[4];
  #pragma unroll
  for (int n = 0; n < 4; ++n) bv[n] = bias[cn0 + n * 16 + (L & 15)];
  if (OBJ) {
    float w2v[4];
    #pragma unroll
    for (int n = 0; n < 4; ++n) w2v[n] = w2[cn0 + n * 16 + (L & 15)];
    float* op = objp + (size_t)(bn * 2 + wn) * KM;
    #pragma unroll
    for (int m = 0; m < 4; ++m) {
      int grow0 = bm * 128 + wm * 64 + m * 16 + ((L >> 4) << 2);
      #pragma unroll
      for (int r = 0; r < 4; ++r) {
        float s = 0.f;
        #pragma unroll
        for (int n = 0; n < 4; ++n) {
          float v = gelu_exact(acc[m][n][r] + bv[n]);
          s += v * w2v[n];
        }
        s += __shfl_xor(s, 1); s += __shfl_xor(s, 2);
        s += __shfl_xor(s, 4); s += __shfl_xor(s, 8);
        if ((L & 15) == 0) op[grow0 + r] = s;
      }
    }
  } else {
    #pragma unroll
    for (int m = 0; m < 4; ++m) {
      int grow0 = bm * 128 + wm * 64 + m * 16 + ((L >> 4) << 2);
      #pragma unroll
      for (int r = 0; r < 4; ++r) {
        size_t ro = (size_t)(grow0 + r) * N;
        #pragma unroll
        for (int n = 0; n < 4; ++n) {
          float v = acc[m][n][r] + bv[n];
          if (ACT == 1) v = gelu_exact(v);
          int col = cn0 + n * 16 + (L & 15);
          if (RES) v += (float)res[ro + col];
          C[ro + col] = (bf16)v;
        }
      }
    }
  }
}

// ---------------- LayerNorm, one row per WAVE (no barriers) ----------------
__global__ void ln_wave_kernel(bf16* __restrict__ X, const float* __restrict__ g,
                               const float* __restrict__ b) {
  int w = threadIdx.x >> 6, L = threadIdx.x & 63;
  size_t row = (size_t)blockIdx.x * 4 + w;
  bf16* xr = X + row * 1024 + L * 16;
  bf16x8 v0 = *reinterpret_cast<const bf16x8*>(xr);
  bf16x8 v1 = *reinterpret_cast<const bf16x8*>(xr + 8);
  float x[16];
  #pragma unroll
  for (int i = 0; i < 8; ++i) { x[i] = (float)v0[i]; x[8 + i] = (float)v1[i]; }
  float s = 0.f;
  #pragma unroll
  for (int i = 0; i < 16; ++i) s += x[i];
  #pragma unroll
  for (int off = 32; off > 0; off >>= 1) s += __shfl_xor(s, off);
  float mu = s * (1.0f / 1024.0f);
  float sq = 0.f;
  #pragma unroll
  for (int i = 0; i < 16; ++i) { x[i] -= mu; sq += x[i] * x[i]; }
  #pragma unroll
  for (int off = 32; off > 0; off >>= 1) sq += __shfl_xor(sq, off);
  float rs = rsqrtf(sq * (1.0f / 1024.0f) + 1e-5f);
  const float4* gp = reinterpret_cast<const float4*>(g + L * 16);
  const float4* bp = reinterpret_cast<const float4*>(b + L * 16);
  bf16x8 o0, o1;
  #pragma unroll
  for (int q = 0; q < 4; ++q) {
    float4 gv = gp[q], bv = bp[q];
    int i = q * 4;
    float r0 = x[i] * rs * gv.x + bv.x;
    float r1 = x[i + 1] * rs * gv.y + bv.y;
    float r2 = x[i + 2] * rs * gv.z + bv.z;
    float r3 = x[i + 3] * rs * gv.w + bv.w;
    if (q < 2) { o0[i] = (bf16)r0; o0[i + 1] = (bf16)r1; o0[i + 2] = (bf16)r2; o0[i + 3] = (bf16)r3; }
    else { o1[i - 8] = (bf16)r0; o1[i - 7] = (bf16)r1; o1[i - 6] = (bf16)r2; o1[i - 5] = (bf16)r3; }
  }
  *reinterpret_cast<bf16x8*>(xr) = o0;
  *reinterpret_cast<bf16x8*>(xr + 8) = o1;
}

// ---------------- attn logits via MFMA -> raw logits DIRECT to out_attn ----------------
__global__ void attn_logits_mfma(const bf16* __restrict__ seq, const float* __restrict__ tq,
                                 const float* __restrict__ objp, const float* __restrict__ b2,
                                 float* __restrict__ logits, float* __restrict__ out_obj) {
  __shared__ bf16 tqs[16][1032];
  int tid = threadIdx.x;
  for (int i = tid; i < 4096; i += 256) {
    int idx = i * 4;
    int n = idx >> 10, k = idx & 1023;
    float4 v = *reinterpret_cast<const float4*>(tq + idx);
    bf16x4 p; p[0] = (bf16)v.x; p[1] = (bf16)v.y; p[2] = (bf16)v.z; p[3] = (bf16)v.w;
    *reinterpret_cast<bf16x4*>(&tqs[n][k]) = p;
  }
  __syncthreads();
  int w = tid >> 6, L = tid & 63;
  int row0 = blockIdx.x * 128 + w * 32;
  const bf16* A0 = seq + (size_t)(row0 + (L & 15)) * 1024 + ((L >> 4) * 8);
  const bf16* Bq = &tqs[L & 15][(L >> 4) * 8];
  f32x4 acc0 = {}, acc1 = {};
  #pragma unroll 4
  for (int kt = 0; kt < 32; ++kt) {
    int k0 = kt * 32;
    bf16x8 bq = *reinterpret_cast<const bf16x8*>(Bq + k0);
    bf16x8 a0 = *reinterpret_cast<const bf16x8*>(A0 + k0);
    bf16x8 a1 = *reinterpret_cast<const bf16x8*>(A0 + 16 * 1024 + k0);
    acc0 = __builtin_amdgcn_mfma_f32_16x16x32_bf16(a0, bq, acc0, 0, 0, 0);
    acc1 = __builtin_amdgcn_mfma_f32_16x16x32_bf16(a1, bq, acc1, 0, 0, 0);
  }
  float b2v = b2[0];
  int b = row0 >> 12;
  int n = L & 15;
  float* outn = logits + ((size_t)(b * 16) + n) * 4096;
  #pragma unroll
  for (int mf = 0; mf < 2; ++mf) {
    int mrow = row0 + mf * 16 + ((L >> 4) << 2);
    float os0 = 0.f, os1 = 0.f, os2 = 0.f, os3 = 0.f;
    #pragma unroll
    for (int p = 0; p < 8; ++p) {
      float4 t = *reinterpret_cast<const float4*>(objp + (size_t)p * KM + mrow);
      os0 += t.x; os1 += t.y; os2 += t.z; os3 += t.w;
    }
    float ob[4];
    ob[0] = 1.0f / (1.0f + expf(-(os0 + b2v)));
    ob[1] = 1.0f / (1.0f + expf(-(os1 + b2v)));
    ob[2] = 1.0f / (1.0f + expf(-(os2 + b2v)));
    ob[3] = 1.0f / (1.0f + expf(-(os3 + b2v)));
    #pragma unroll
    for (int r = 0; r < 4; ++r) {
      int m = mrow + r;
      float v = (mf == 0 ? acc0[r] : acc1[r]) * 0.03125f + 1.5f * ob[r];
      outn[m & 4095] = v;
    }
    if (n == 0) {
      float4 o4 = make_float4(ob[0], ob[1], ob[2], ob[3]);
      *reinterpret_cast<float4*>(out_obj + mrow) = o4;
    }
  }
}

// ---------------- softmax over T=4096 per (b,n), IN-PLACE on out_attn ----------------
__global__ void softmax_kernel(float* __restrict__ attn) {
  __shared__ float sb[4];
  size_t row = blockIdx.x;
  float* orow = attn + row * 4096;
  int tid = threadIdx.x;
  float x[16];
  #pragma unroll
  for (int i = 0; i < 4; ++i) {
    float4 v = *reinterpret_cast<const float4*>(orow + tid * 16 + i * 4);
    x[i * 4 + 0] = v.x; x[i * 4 + 1] = v.y; x[i * 4 + 2] = v.z; x[i * 4 + 3] = v.w;
  }
  float mx = -1e30f;
  #pragma unroll
  for (int j = 0; j < 16; ++j) mx = fmaxf(mx, x[j]);
  #pragma unroll
  for (int off = 32; off > 0; off >>= 1) mx = fmaxf(mx, __shfl_xor(mx, off));
  if ((tid & 63) == 0) sb[tid >> 6] = mx;
  __syncthreads();
  mx = fmaxf(fmaxf(sb[0], sb[1]), fmaxf(sb[2], sb[3]));
  __syncthreads();
  float s = 0.f;
  #pragma unroll
  for (int j = 0; j < 16; ++j) { x[j] = expf(x[j] - mx); s += x[j]; }
  #pragma unroll
  for (int off = 32; off > 0; off >>= 1) s += __shfl_xor(s, off);
  if ((tid & 63) == 0) sb[tid >> 6] = s;
  __syncthreads();
  float inv = 1.0f / (sb[0] + sb[1] + sb[2] + sb[3]);
  #pragma unroll
  for (int i = 0; i < 4; ++i) {
    float4 v = make_float4(x[i * 4] * inv, x[i * 4 + 1] * inv, x[i * 4 + 2] * inv, x[i * 4 + 3] * inv);
    *reinterpret_cast<float4*>(orow + tid * 16 + i * 4) = v;
  }
}

// ---------------- token_values: sum_t attn[b,n,t]*seq[b,t,h], T split 16 ways ----------------
__global__ void token_values_kernel(const float* __restrict__ attn, const bf16* __restrict__ seq,
                                    float* __restrict__ tvp) {
  int bid = blockIdx.x;
  int split = bid & 15;
  int hc = (bid >> 4) & 15;
  int b = bid >> 8;
  __shared__ float al[16][256];
  int h = hc * 64 + (threadIdx.x & 63);
  int grp = threadIdx.x >> 6;  // 4 groups x 4 n each
  int t0 = split * 256;
  for (int i = threadIdx.x; i < 4096; i += 256)
    al[i >> 8][i & 255] = attn[((size_t)b * 16 + (i >> 8)) * 4096 + t0 + (i & 255)];
  __syncthreads();
  float acc[4] = {0.f, 0.f, 0.f, 0.f};
  for (int tt = 0; tt < 256; ++tt) {
    float s = (float)seq[((size_t)b * 4096 + t0 + tt) * 1024 + h];
    #pragma unroll
    for (int i = 0; i < 4; ++i) acc[i] += al[grp * 4 + i][tt] * s;
  }
  #pragma unroll
  for (int i = 0; i < 4; ++i)
    tvp[(size_t)split * 131072 + ((size_t)b * 16 + grp * 4 + i) * 1024 + h] = acc[i];
}

// ---------------- final LN: LN(tq + sum_16_parts(tv)) -> fp32 out ----------------
__global__ void final_ln_kernel(const float* __restrict__ tq, const float* __restrict__ tvp,
                                const float* __restrict__ g, const float* __restrict__ bb,
                                float* __restrict__ out0) {
  __shared__ float sb[4];
  int row = blockIdx.x;
  int n = row & 15;
  int tid = threadIdx.x;
  float x[4];
  #pragma unroll
  for (int i = 0; i < 4; ++i) {
    int h = tid * 4 + i;
    float v = tq[n * 1024 + h];
    #pragma unroll
    for (int p = 0; p < 16; ++p) v += tvp[(size_t)p * 131072 + (size_t)row * 1024 + h];
    x[i] = v;
  }
  float s = x[0] + x[1] + x[2] + x[3];
  #pragma unroll
  for (int off = 32; off > 0; off >>= 1) s += __shfl_xor(s, off);
  if ((tid & 63) == 0) sb[tid >> 6] = s;
  __syncthreads();
  float mu = (sb[0] + sb[1] + sb[2] + sb[3]) * (1.0f / 1024.0f);
  __syncthreads();
  float d[4], sq = 0.f;
  #pragma unroll
  for (int i = 0; i < 4; ++i) { d[i] = x[i] - mu; sq += d[i] * d[i]; }
  #pragma unroll
  for (int off = 32; off > 0; off >>= 1) sq += __shfl_xor(sq, off);
  if ((tid & 63) == 0) sb[tid >> 6] = sq;
  __syncthreads();
  float var = (sb[0] + sb[1] + sb[2] + sb[3]) * (1.0f / 1024.0f);
  float rs = rsqrtf(var + 1e-5f);
  #pragma unroll
  for (int i = 0; i < 4; ++i) {
    int h = tid * 4 + i;
    out0[(size_t)row * 1024 + h] = d[i] * rs * g[h] + bb[h];
  }
}

extern "C" void kernel_launch(void* const* d_in, const int* in_sizes, int n_in,
                              void* d_out, int out_size, void* d_ws, size_t ws_size,
                              hipStream_t stream) {
  const float* tr      = (const float*)d_in[0];
  const float* se      = (const float*)d_in[1];
  const float* pr      = (const float*)d_in[2];
  const float* W_in    = (const float*)d_in[3];
  const float* b_in    = (const float*)d_in[4];
  const float* ln_in_g = (const float*)d_in[5];
  const float* ln_in_b = (const float*)d_in[6];
  const float* W_m1    = (const float*)d_in[7];
  const float* b_m1    = (const float*)d_in[8];
  const float* W_m2    = (const float*)d_in[9];
  const float* b_m2    = (const float*)d_in[10];
  const float* W_o1    = (const float*)d_in[11];
  const float* b_o1    = (const float*)d_in[12];
  const float* W_o2    = (const float*)d_in[13];
  const float* b_o2    = (const float*)d_in[14];
  const float* tq      = (const float*)d_in[15];
  const float* ln_out_g= (const float*)d_in[16];
  const float* ln_out_b= (const float*)d_in[17];

  float* out       = (float*)d_out;
  float* out_state = out;                       // [8,16,1024]
  float* out_attn  = out + 131072;              // [8,16,4096]
  float* out_obj   = out + 131072 + 524288;     // [8,4096]

  char* ws = (char*)d_ws;
  size_t off = 0;
  auto alloc = [&](size_t bytes) {
    char* p = ws + off;
    off += (bytes + 255) & ~(size_t)255;
    return p;
  };
  bf16*  Xb   = (bf16*)alloc(71303168);   // fused input; reused as t1
  bf16*  t1   = Xb;
  bf16*  hb   = (bf16*)alloc(67108864);   // h (residual source)
  bf16*  sq   = (bf16*)alloc(67108864);   // h+mlp -> seq_hidden (LN in place)
  bf16*  WbIn = (bf16*)alloc(2228224);
  bf16*  WbM1 = (bf16*)alloc(2097152);
  bf16*  WbM2 = (bf16*)alloc(2097152);
  bf16*  WbO1 = (bf16*)alloc(1048576);
  float* objp = (float*)alloc(8 * KM * 4);   // 8 deterministic obj partials per row
  float* tvp  = (float*)alloc(16 * 131072 * 4);  // 16 tv partials

  fuse_transpose_kernel<<<34816 + 3648, 256, 0, stream>>>(
      tr, se, pr, Xb, W_in, W_m1, W_m2, W_o1, WbIn, WbM1, WbM2, WbO1);

  // h = fused@W_in + b_in
  gemm_kernel<0, false, false><<<2048, 256, 0, stream>>>(
      Xb, WbIn, b_in, nullptr, hb, nullptr, nullptr, 1024, 1088, 8);
  // t1 = gelu(h@W_m1 + b_m1)
  gemm_kernel<1, false, false><<<2048, 256, 0, stream>>>(
      hb, WbM1, b_m1, nullptr, t1, nullptr, nullptr, 1024, 1024, 8);
  // s = h + (t1@W_m2 + b_m2)
  gemm_kernel<0, true, false><<<2048, 256, 0, stream>>>(
      t1, WbM2, b_m2, hb, sq, nullptr, nullptr, 1024, 1024, 8);
  // seq_hidden = LN(s)  — one row per wave
  ln_wave_kernel<<<8192, 256, 0, stream>>>(sq, ln_in_g, ln_in_b);
  // objectness partials: gelu(seq@W_o1+b_o1) . W_o2  (no o1 materialization)
  gemm_kernel<1, false, true><<<1024, 256, 0, stream>>>(
      sq, WbO1, b_o1, nullptr, nullptr, W_o2, objp, 512, 1024, 4);
  // attn raw logits -> out_attn directly; sigmoid(obj) -> out_obj
  attn_logits_mfma<<<256, 256, 0, stream>>>(sq, tq, objp, b_o2, out_attn, out_obj);
  // softmax in place
  softmax_kernel<<<128, 256, 0, stream>>>(out_attn);
  // token values (16-way split) + final LN
  token_values_kernel<<<2048, 256, 0, stream>>>(out_attn, sq, tvp);
  final_ln_kernel<<<128, 256, 0, stream>>>(tq, tvp, ln_out_g, ln_out_b, out_state);
}